// Round 1
// baseline (93.129 us; speedup 1.0000x reference)
//
#include <hip/hip_runtime.h>

#define HDIM 1024
#define NW 18            // 6 gate rows + 12 expert rows (e*2+l)
#define ROWS_PER_BLOCK 128
#define NTHREADS 256

// Layout notes:
//  - Each row of cls (1024 f32 = 4KB) is processed by a 4-lane cluster:
//    lane l: row-slot s = l>>2 (16 rows/wave-slot), col-chunk c = l&3 (256 cols each).
//  - R=2 rows per lane (row s and s+16) -> 32 rows/wave, 128 rows/block.
//  - Weights for all 18 dots live in LDS, slot-major float4 with XOR swizzle so the
//    4 distinct broadcast addresses per iteration hit 4 distinct bank groups.
__global__ __launch_bounds__(NTHREADS, 2)
void hardmoe_kernel(const float* __restrict__ cls,
                    const float* __restrict__ gate_w,
                    const float* __restrict__ gate_b,
                    const float* __restrict__ expert_w,
                    const float* __restrict__ expert_b,
                    float* __restrict__ out, int B)
{
    // LDS: slot-major [256 slots][18 w] float4 = 72 KB
    __shared__ float4 Wl[256 * NW];

    const int t = threadIdx.x;

    // ---- Stage weights into LDS (coalesced global reads, swizzled LDS placement) ----
    // float4 f over [w (18)][s (256)]
    for (int i = 0; i < NW * 256; i += NTHREADS) {
        int f = i + t;
        int w = f >> 8;          // 0..17
        int s = f & 255;         // float4 slot within the 1024-col row
        int cc = s >> 6;         // col chunk 0..3
        int jj = s & 63;         // iter index within chunk
        const float* src = (w < 6) ? (gate_w + (size_t)w * HDIM)
                                   : (expert_w + (size_t)(w - 6) * HDIM);
        float4 v = *reinterpret_cast<const float4*>(src + s * 4);
        int slot = (cc << 6) | (jj ^ cc);       // XOR swizzle
        Wl[slot * NW + w] = v;
    }
    __syncthreads();

    // ---- Biases into registers (uniform -> scalar loads) ----
    float gb[6], eb[12];
#pragma unroll
    for (int e = 0; e < 6; ++e) gb[e] = gate_b[e];
#pragma unroll
    for (int k = 0; k < 12; ++k) eb[k] = expert_b[k];

    const int wv = t >> 6;       // wave 0..3
    const int l  = t & 63;
    const int s  = l >> 2;       // row slot 0..15
    const int c  = l & 3;        // col chunk 0..3

    const int rowbase = blockIdx.x * ROWS_PER_BLOCK + wv * 32;
    int row0 = rowbase + s;
    int row1 = rowbase + s + 16;
    // Clamp (B is a multiple of 128 in this problem; keep a cheap guard)
    int r0c = row0 < B ? row0 : B - 1;
    int r1c = row1 < B ? row1 : B - 1;

    const float* p0 = cls + (size_t)r0c * HDIM + c * 256;
    const float* p1 = cls + (size_t)r1c * HDIM + c * 256;

    float a0[NW], a1[NW];
#pragma unroll
    for (int w = 0; w < NW; ++w) { a0[w] = 0.f; a1[w] = 0.f; }

#pragma unroll 2
    for (int j = 0; j < 64; ++j) {
        float4 x0 = *reinterpret_cast<const float4*>(p0 + j * 4);
        float4 x1 = *reinterpret_cast<const float4*>(p1 + j * 4);
        const float4* wp = &Wl[(size_t)(((c << 6) | (j ^ c)) * NW)];
#pragma unroll
        for (int w = 0; w < NW; ++w) {
            float4 wf = wp[w];
            a0[w] += x0.x * wf.x + x0.y * wf.y + x0.z * wf.z + x0.w * wf.w;
            a1[w] += x1.x * wf.x + x1.y * wf.y + x1.z * wf.z + x1.w * wf.w;
        }
    }

    // ---- Reduce across the 4-lane cluster (c dimension): xor 1, xor 2 ----
#pragma unroll
    for (int w = 0; w < NW; ++w) {
        a0[w] += __shfl_xor(a0[w], 1);
        a0[w] += __shfl_xor(a0[w], 2);
        a1[w] += __shfl_xor(a1[w], 1);
        a1[w] += __shfl_xor(a1[w], 2);
    }

    // ---- Finalize: gate argmax (first-max tiebreak) + expert select + bias ----
    // Done redundantly on all 4 lanes of a cluster; lane c==0 stores.
    {
        float best = a0[0] + gb[0];
        int idx = 0;
#pragma unroll
        for (int e = 1; e < 6; ++e) {
            float v = a0[e] + gb[e];
            if (v > best) { best = v; idx = e; }
        }
        float o0 = 0.f, o1 = 0.f;
#pragma unroll
        for (int e = 0; e < 6; ++e) {
            bool m = (idx == e);
            o0 = m ? (a0[6 + 2 * e] + eb[2 * e])     : o0;
            o1 = m ? (a0[7 + 2 * e] + eb[2 * e + 1]) : o1;
        }
        if (c == 0 && row0 < B)
            *reinterpret_cast<float2*>(out + (size_t)row0 * 2) = make_float2(o0, o1);
    }
    {
        float best = a1[0] + gb[0];
        int idx = 0;
#pragma unroll
        for (int e = 1; e < 6; ++e) {
            float v = a1[e] + gb[e];
            if (v > best) { best = v; idx = e; }
        }
        float o0 = 0.f, o1 = 0.f;
#pragma unroll
        for (int e = 0; e < 6; ++e) {
            bool m = (idx == e);
            o0 = m ? (a1[6 + 2 * e] + eb[2 * e])     : o0;
            o1 = m ? (a1[7 + 2 * e] + eb[2 * e + 1]) : o1;
        }
        if (c == 0 && row1 < B)
            *reinterpret_cast<float2*>(out + (size_t)row1 * 2) = make_float2(o0, o1);
    }
}

extern "C" void kernel_launch(void* const* d_in, const int* in_sizes, int n_in,
                              void* d_out, int out_size, void* d_ws, size_t ws_size,
                              hipStream_t stream) {
    const float* cls      = (const float*)d_in[0];
    const float* gate_w   = (const float*)d_in[1];
    const float* gate_b   = (const float*)d_in[2];
    const float* expert_w = (const float*)d_in[3];
    const float* expert_b = (const float*)d_in[4];
    float* out = (float*)d_out;

    const int B = in_sizes[0] / HDIM;
    const int grid = (B + ROWS_PER_BLOCK - 1) / ROWS_PER_BLOCK;

    hardmoe_kernel<<<grid, NTHREADS, 0, stream>>>(cls, gate_w, gate_b,
                                                  expert_w, expert_b, out, B);
}